// Round 6
// baseline (3098.136 us; speedup 1.0000x reference)
//
#include <hip/hip_runtime.h>
#include <math.h>

// RecurrentUnitAtt on MI355X — round 6 (resubmit of v2; R3-R5 never ran:
// GPU acquisition timeouts). R2 data: fused_main_k 1459us, VGPR=256, Occ 12%,
// VALU 16.5%, WRITE 333MB vs 8.4MB ideal => register-spill bound. v2 fix:
// channel-split — wave = 1 point, lane = (neighbor k, channel-quarter c),
// acc arrays [16] instead of [64]; cross-channel exchange via per-wave LDS.

#define NPTS 4096
#define CF   64

#define OFF_R0 0
#define OFF_Z0 4288
#define OFF_H0 8576
#define OFF_R1 12864
#define OFF_RO 16960
#define OFF_Z1 21056
#define OFF_H1 25152
#define OFF_FR 29248
#define OFF_FZ 33344

__global__ __launch_bounds__(256) void prep_weights_k(
    const float* __restrict__ w_r0, const float* __restrict__ w_z0,
    const float* __restrict__ w_h0, const float* __restrict__ w_r1,
    const float* __restrict__ w_ro, const float* __restrict__ w_z1,
    const float* __restrict__ w_h1, const float* __restrict__ w_fr,
    const float* __restrict__ w_fz, float* __restrict__ wT)
{
  const float* src; float* dst; int C;
  switch (blockIdx.x) {
    case 0: src = w_r0; dst = wT + OFF_R0; C = 67; break;
    case 1: src = w_z0; dst = wT + OFF_Z0; C = 67; break;
    case 2: src = w_h0; dst = wT + OFF_H0; C = 67; break;
    case 3: src = w_r1; dst = wT + OFF_R1; C = 64; break;
    case 4: src = w_ro; dst = wT + OFF_RO; C = 64; break;
    case 5: src = w_z1; dst = wT + OFF_Z1; C = 64; break;
    case 6: src = w_h1; dst = wT + OFF_H1; C = 64; break;
    case 7: src = w_fr; dst = wT + OFF_FR; C = 64; break;
    default: src = w_fz; dst = wT + OFF_FZ; C = 64; break;
  }
  const int total = C * 64;
  for (int e = threadIdx.x; e < total; e += 256) {
    int c = e >> 6, o = e & 63;
    dst[c * 64 + o] = src[o * C + c];   // wT[c][o] = w[o][c]
  }
}

// p2 -> p2T (blocks 0..511) and p1 -> p1T (blocks 512..1023, only if launched)
__global__ __launch_bounds__(256) void transpose_in_k(
    const float* __restrict__ p2, const float* __restrict__ p1,
    float* __restrict__ p2T, float* __restrict__ p1T)
{
  __shared__ float tile[64][65];
  int id = blockIdx.x;
  const float* src; float* dst; int sub;
  if (id < 512) { sub = id;       src = p2; dst = p2T; }
  else          { sub = id - 512; src = p1; dst = p1T; }
  const int b  = sub >> 6;
  const int n0 = (sub & 63) * 64;
  src += (size_t)b * CF * NPTS;
  for (int e = threadIdx.x; e < 4096; e += 256) {
    int cc = e >> 6, nn = e & 63;
    tile[cc][nn] = src[(size_t)cc * NPTS + n0 + nn];
  }
  __syncthreads();
  float* d2 = dst + ((size_t)b * NPTS + n0) * CF;
  for (int e = threadIdx.x; e < 4096; e += 256) {
    int nn = e >> 6, cc = e & 63;
    d2[(size_t)nn * CF + cc] = tile[cc][nn];
  }
}

// outT [B,N,64] -> out [B,64,N]
__global__ __launch_bounds__(256) void transpose_out_k(
    const float* __restrict__ outT, float* __restrict__ outp)
{
  __shared__ float tile[64][65];
  const int b  = blockIdx.x >> 6;
  const int n0 = (blockIdx.x & 63) * 64;
  const float* src = outT + ((size_t)b * NPTS + n0) * CF;
  for (int e = threadIdx.x; e < 4096; e += 256) {
    int nn = e >> 6, cc = e & 63;
    tile[cc][nn] = src[(size_t)nn * CF + cc];
  }
  __syncthreads();
  float* dst = outp + (size_t)b * CF * NPTS + n0;
  for (int e = threadIdx.x; e < 4096; e += 256) {
    int cc = e >> 6, nn = e & 63;
    dst[(size_t)cc * NPTS + nn] = tile[cc][nn];
  }
}

// ---------------- kNN (unchanged from R2: passed) ----------------

__device__ __forceinline__ float max16_(const float (&ld)[16]) {
  float a0 = fmaxf(ld[0], ld[1]);
  float a1 = fmaxf(ld[2], ld[3]);
  float a2 = fmaxf(ld[4], ld[5]);
  float a3 = fmaxf(ld[6], ld[7]);
  float a4 = fmaxf(ld[8], ld[9]);
  float a5 = fmaxf(ld[10], ld[11]);
  float a6 = fmaxf(ld[12], ld[13]);
  float a7 = fmaxf(ld[14], ld[15]);
  a0 = fmaxf(a0, a1); a2 = fmaxf(a2, a3); a4 = fmaxf(a4, a5); a6 = fmaxf(a6, a7);
  return fmaxf(fmaxf(a0, a2), fmaxf(a4, a6));
}

__device__ __forceinline__ void insert16_(float (&ld)[16], int (&li)[16],
                                          float& dmax, float d, int m) {
  bool done = false;
  #pragma unroll
  for (int j = 0; j < 16; ++j) {
    bool hit = (!done) && (ld[j] == dmax);
    if (hit) { ld[j] = d; li[j] = m; }
    done = done || hit;
  }
  dmax = max16_(ld);
}

__global__ __launch_bounds__(256) void knn_k(const float* __restrict__ xyz1,
                                             const float* __restrict__ xyz2,
                                             int* __restrict__ idx_out)
{
  __shared__ float4 stage[2048];
  __shared__ float bd[4][64][17];
  __shared__ unsigned short bix[4][64][17];
  const int t    = threadIdx.x;
  const int b    = blockIdx.x >> 6;
  const int q0   = (blockIdx.x & 63) * 64;
  const int lane = t & 63;
  const int seg  = t >> 6;
  const int q    = q0 + lane;
  const float* x1b = xyz1 + (size_t)b * 3 * NPTS;
  const float* x2b = xyz2 + (size_t)b * 3 * NPTS;
  const float qx = x1b[q], qy = x1b[NPTS + q], qz = x1b[2 * NPTS + q];
  const float qq = qx * qx + qy * qy + qz * qz;
  float ld[16]; int li[16];
  #pragma unroll
  for (int j = 0; j < 16; ++j) { ld[j] = 3.4e38f; li[j] = 0; }
  float dmax = 3.4e38f;
  for (int pass = 0; pass < 2; ++pass) {
    const int mbase = pass * 2048;
    for (int i = t; i < 2048; i += 256) {
      const int mm = mbase + i;
      float px = x2b[mm], py = x2b[NPTS + mm], pz = x2b[2 * NPTS + mm];
      stage[i] = make_float4(px, py, pz, px * px + py * py + pz * pz);
    }
    __syncthreads();
    const int s0 = seg * 512;
    #pragma unroll 4
    for (int i = 0; i < 512; ++i) {
      float4 P = stage[s0 + i];
      float d = fmaf(-2.f, fmaf(qx, P.x, fmaf(qy, P.y, qz * P.z)), qq + P.w);
      if (d < dmax) insert16_(ld, li, dmax, d, mbase + s0 + i);
    }
    __syncthreads();
  }
  #pragma unroll
  for (int j = 0; j < 16; ++j) {
    bd[seg][lane][j]  = ld[j];
    bix[seg][lane][j] = (unsigned short)li[j];
  }
  __syncthreads();
  if (t < 64) {
    float md[16]; int mi[16];
    #pragma unroll
    for (int j = 0; j < 16; ++j) { md[j] = 3.4e38f; mi[j] = 0; }
    float mmax = 3.4e38f;
    for (int s = 0; s < 4; ++s) {
      #pragma unroll 4
      for (int j = 0; j < 16; ++j) {
        float d = bd[s][t][j];
        if (d < mmax) insert16_(md, mi, mmax, d, (int)bix[s][t][j]);
      }
    }
    int* op = idx_out + ((size_t)b * NPTS + q0 + t) * 16;
    #pragma unroll
    for (int j = 0; j < 16; ++j) op[j] = mi[j];
  }
}

// ---------------- fused gates v2: channel-split ----------------

__device__ __forceinline__ float sigmoidf_(float x) { return 1.0f / (1.0f + __expf(-x)); }
__device__ __forceinline__ float tanhf_(float x) {
  float s = __expf(-2.0f * fabsf(x));
  float r = (1.0f - s) / (1.0f + s);
  return x >= 0.0f ? r : -r;
}
__device__ __forceinline__ float leakyf_(float x) { return fmaxf(x, 0.0f) + 0.1f * fminf(x, 0.0f); }

__device__ __forceinline__ void fma16(const float* __restrict__ wr, float s, float (&a)[16]) {
  #pragma unroll
  for (int j4 = 0; j4 < 4; ++j4) {
    float4 wv = *(const float4*)(wr + j4 * 4);
    a[j4 * 4 + 0] = fmaf(s, wv.x, a[j4 * 4 + 0]);
    a[j4 * 4 + 1] = fmaf(s, wv.y, a[j4 * 4 + 1]);
    a[j4 * 4 + 2] = fmaf(s, wv.z, a[j4 * 4 + 2]);
    a[j4 * 4 + 3] = fmaf(s, wv.w, a[j4 * 4 + 3]);
  }
}

// a[j] += sum_{cin=0..63} in_row[cin] * wg[cin*64 + og + j]
__device__ __forceinline__ void mat64x16(const float* in_row, const float* __restrict__ wg,
                                         int og, float (&a)[16]) {
  #pragma unroll 1
  for (int c4 = 0; c4 < 16; ++c4) {
    float4 v = *(const float4*)(in_row + c4 * 4);     // LDS b128
    fma16(wg + (c4 * 4 + 0) * 64 + og, v.x, a);
    fma16(wg + (c4 * 4 + 1) * 64 + og, v.y, a);
    fma16(wg + (c4 * 4 + 2) * 64 + og, v.z, a);
    fma16(wg + (c4 * 4 + 3) * 64 + og, v.w, a);
  }
}

// conv0: 64 features + 3 direction rows
__device__ __forceinline__ void conv0g(const float* np_row, const float* __restrict__ wg,
                                       int og, float (&a)[16]) {
  mat64x16(np_row, wg, og, a);
  float d0 = np_row[64], d1 = np_row[65], d2 = np_row[66];
  fma16(wg + 64 * 64 + og, d0, a);
  fma16(wg + 65 * 64 + og, d1, a);
  fma16(wg + 66 * 64 + og, d2, a);
}

// Per-point [64]->[64] layer, distributed: this lane's partial over its 16-input
// group for 4 outputs (k4..k4+3), then butterfly-sum over the 4 c-lanes.
__device__ __forceinline__ float4 plsum(const float (&pl)[16], const float* __restrict__ w1,
                                        int og, int k4) {
  float a0 = 0.f, a1 = 0.f, a2 = 0.f, a3 = 0.f;
  #pragma unroll 1
  for (int j = 0; j < 16; ++j) {
    float4 wv = *(const float4*)(w1 + (og + j) * 64 + k4);
    a0 = fmaf(pl[j], wv.x, a0);
    a1 = fmaf(pl[j], wv.y, a1);
    a2 = fmaf(pl[j], wv.z, a2);
    a3 = fmaf(pl[j], wv.w, a3);
  }
  a0 += __shfl_xor(a0, 1); a1 += __shfl_xor(a1, 1);
  a2 += __shfl_xor(a2, 1); a3 += __shfl_xor(a3, 1);
  a0 += __shfl_xor(a0, 2); a1 += __shfl_xor(a1, 2);
  a2 += __shfl_xor(a2, 2); a3 += __shfl_xor(a3, 2);
  return make_float4(a0, a1, a2, a3);
}

// block = 256 = 4 waves; wave = 1 point; lane = k*4 + c (k = neighbor, c = ch-quarter)
__global__ __launch_bounds__(256) void fused_main_k(
    const float* __restrict__ xyz1, const float* __restrict__ xyz2,
    const float* __restrict__ p1,   const float* __restrict__ p1T,
    const float* __restrict__ p2T,  const int* __restrict__ knn_idx,
    const float* __restrict__ wT,
    const float* __restrict__ b_r0, const float* __restrict__ b_r1,
    const float* __restrict__ b_z0, const float* __restrict__ b_z1,
    const float* __restrict__ b_h0, const float* __restrict__ b_h1,
    float* __restrict__ outp, float* __restrict__ outT,
    int use_p1T, int use_outT)
{
  __shared__ float np_s[4][16][68];   // 64 feat + 3 dir (+pad); 272B rows, 16B-aligned
  __shared__ float rs_s[4][16][68];   // exchange: leaky(racc), then rp
  __shared__ float p1s[4][64];
  __shared__ float frs[4][64], fzs[4][64];
  __shared__ float zs[4][64],  hs[4][64];

  const int t    = threadIdx.x;
  const int wv   = t >> 6;
  const int lane = t & 63;
  const int k    = lane >> 2;
  const int c    = lane & 3;
  const int og   = c * 16;
  const int k4   = k * 4;

  const long pid = (long)blockIdx.x * 4 + wv;        // global point id, 0..32767
  const int b = (int)(pid >> 12);
  const int n = (int)(pid & 4095);

  const float* x1b = xyz1 + (size_t)b * 3 * NPTS;
  const float* x2b = xyz2 + (size_t)b * 3 * NPTS;

  // ---- stage: p1 row, neighbor rows + direction ----
  if (use_p1T) p1s[wv][lane] = p1T[(size_t)pid * 64 + lane];
  else         p1s[wv][lane] = p1[(size_t)b * CF * NPTS + (size_t)lane * NPTS + n];

  const int m = knn_idx[(size_t)pid * 16 + k];
  {
    const float* src = p2T + ((size_t)b * NPTS + m) * 64 + og;
    float4 v0 = *(const float4*)(src);
    float4 v1 = *(const float4*)(src + 4);
    float4 v2 = *(const float4*)(src + 8);
    float4 v3 = *(const float4*)(src + 12);
    *(float4*)(&np_s[wv][k][og])      = v0;
    *(float4*)(&np_s[wv][k][og + 4])  = v1;
    *(float4*)(&np_s[wv][k][og + 8])  = v2;
    *(float4*)(&np_s[wv][k][og + 12]) = v3;
    if (c == 0) {
      np_s[wv][k][64] = x2b[m]            - x1b[n];
      np_s[wv][k][65] = x2b[NPTS + m]     - x1b[NPTS + n];
      np_s[wv][k][66] = x2b[2 * NPTS + m] - x1b[2 * NPTS + n];
    }
  }
  __syncthreads();

  // ---- fuse_r / fuse_z (per point; lane partial over its c-group, 4 outs k4..) ----
  {
    float p1loc[16];
    #pragma unroll
    for (int j4 = 0; j4 < 4; ++j4)
      *(float4*)(&p1loc[j4 * 4]) = *(const float4*)(&p1s[wv][og + j4 * 4]);
    float4 fr = plsum(p1loc, wT + OFF_FR, og, k4);
    float4 fz = plsum(p1loc, wT + OFF_FZ, og, k4);
    if (c == 0) {
      *(float4*)(&frs[wv][k4]) = fr;
      *(float4*)(&fzs[wv][k4]) = fz;
    }
  }
  __syncthreads();

  const float* nprow = &np_s[wv][k][0];

  // ---- z gate ----
  {
    float za[16];
    #pragma unroll
    for (int j4 = 0; j4 < 4; ++j4) {
      float4 bb = *(const float4*)(b_z0 + og + j4 * 4);
      float4 ff = *(const float4*)(&fzs[wv][og + j4 * 4]);
      za[j4 * 4 + 0] = bb.x + ff.x; za[j4 * 4 + 1] = bb.y + ff.y;
      za[j4 * 4 + 2] = bb.z + ff.z; za[j4 * 4 + 3] = bb.w + ff.w;
    }
    conv0g(nprow, wT + OFF_Z0, og, za);
    #pragma unroll
    for (int j = 0; j < 16; ++j) za[j] = leakyf_(za[j]);
    #pragma unroll
    for (int j = 0; j < 16; ++j) {           // max-pool over the 16 k-lanes
      float v = za[j];
      v = fmaxf(v, __shfl_xor(v, 4));
      v = fmaxf(v, __shfl_xor(v, 8));
      v = fmaxf(v, __shfl_xor(v, 16));
      v = fmaxf(v, __shfl_xor(v, 32));
      za[j] = v;
    }
    float4 s  = plsum(za, wT + OFF_Z1, og, k4);
    float4 bb = *(const float4*)(b_z1 + k4);
    if (c == 0) {
      *(float4*)(&zs[wv][k4]) = make_float4(
          sigmoidf_(s.x + bb.x), sigmoidf_(s.y + bb.y),
          sigmoidf_(s.z + bb.z), sigmoidf_(s.w + bb.w));
    }
  }

  // ---- r gate conv0 -> leaky -> LDS ----
  {
    float ra[16];
    #pragma unroll
    for (int j4 = 0; j4 < 4; ++j4) {
      float4 bb = *(const float4*)(b_r0 + og + j4 * 4);
      float4 ff = *(const float4*)(&frs[wv][og + j4 * 4]);
      ra[j4 * 4 + 0] = bb.x + ff.x; ra[j4 * 4 + 1] = bb.y + ff.y;
      ra[j4 * 4 + 2] = bb.z + ff.z; ra[j4 * 4 + 3] = bb.w + ff.w;
    }
    conv0g(nprow, wT + OFF_R0, og, ra);
    #pragma unroll
    for (int j = 0; j < 16; ++j) ra[j] = leakyf_(ra[j]);
    #pragma unroll
    for (int j4 = 0; j4 < 4; ++j4)
      *(float4*)(&rs_s[wv][k][og + j4 * 4]) =
          make_float4(ra[j4 * 4], ra[j4 * 4 + 1], ra[j4 * 4 + 2], ra[j4 * 4 + 3]);
  }
  __syncthreads();

  // ---- r1 -> sigmoid -> rp = r * p1 -> LDS (overwrite rs_s) ----
  {
    float a[16];
    #pragma unroll
    for (int j4 = 0; j4 < 4; ++j4)
      *(float4*)(&a[j4 * 4]) = *(const float4*)(b_r1 + og + j4 * 4);
    mat64x16(&rs_s[wv][k][0], wT + OFF_R1, og, a);
    float rp[16];
    #pragma unroll
    for (int j = 0; j < 16; ++j) rp[j] = sigmoidf_(a[j]) * p1s[wv][og + j];
    __syncthreads();
    #pragma unroll
    for (int j4 = 0; j4 < 4; ++j4)
      *(float4*)(&rs_s[wv][k][og + j4 * 4]) =
          make_float4(rp[j4 * 4], rp[j4 * 4 + 1], rp[j4 * 4 + 2], rp[j4 * 4 + 3]);
  }
  __syncthreads();

  // ---- h candidate: pe (rp @ w_ro) + conv0_h -> leaky -> pool -> h1 -> tanh ----
  {
    float ha[16];
    #pragma unroll
    for (int j4 = 0; j4 < 4; ++j4)
      *(float4*)(&ha[j4 * 4]) = *(const float4*)(b_h0 + og + j4 * 4);
    mat64x16(&rs_s[wv][k][0], wT + OFF_RO, og, ha);   // pe
    conv0g(nprow, wT + OFF_H0, og, ha);
    #pragma unroll
    for (int j = 0; j < 16; ++j) ha[j] = leakyf_(ha[j]);
    #pragma unroll
    for (int j = 0; j < 16; ++j) {
      float v = ha[j];
      v = fmaxf(v, __shfl_xor(v, 4));
      v = fmaxf(v, __shfl_xor(v, 8));
      v = fmaxf(v, __shfl_xor(v, 16));
      v = fmaxf(v, __shfl_xor(v, 32));
      ha[j] = v;
    }
    float4 s  = plsum(ha, wT + OFF_H1, og, k4);
    float4 bb = *(const float4*)(b_h1 + k4);
    if (c == 0) {
      *(float4*)(&hs[wv][k4]) = make_float4(
          tanhf_(s.x + bb.x), tanhf_(s.y + bb.y),
          tanhf_(s.z + bb.z), tanhf_(s.w + bb.w));
    }
  }
  __syncthreads();

  // ---- GRU update, coalesced write ----
  {
    float z = zs[wv][lane], h = hs[wv][lane], p = p1s[wv][lane];
    float o = (1.0f - z) * p + z * h;
    if (use_outT) outT[(size_t)pid * 64 + lane] = o;
    else          outp[(size_t)b * CF * NPTS + (size_t)lane * NPTS + n] = o;
  }
}

extern "C" void kernel_launch(void* const* d_in, const int* in_sizes, int n_in,
                              void* d_out, int out_size, void* d_ws, size_t ws_size,
                              hipStream_t stream)
{
  (void)in_sizes; (void)n_in; (void)out_size;
  const float* xyz1 = (const float*)d_in[0];
  const float* xyz2 = (const float*)d_in[1];
  const float* p1   = (const float*)d_in[2];
  const float* p2   = (const float*)d_in[3];
  const float* w_fr = (const float*)d_in[4];
  const float* w_fz = (const float*)d_in[5];
  const float* w_ro = (const float*)d_in[6];
  const float* w_r0 = (const float*)d_in[7];
  const float* b_r0 = (const float*)d_in[8];
  const float* w_r1 = (const float*)d_in[9];
  const float* b_r1 = (const float*)d_in[10];
  const float* w_z0 = (const float*)d_in[11];
  const float* b_z0 = (const float*)d_in[12];
  const float* w_z1 = (const float*)d_in[13];
  const float* b_z1 = (const float*)d_in[14];
  const float* w_h0 = (const float*)d_in[15];
  const float* b_h0 = (const float*)d_in[16];
  const float* w_h1 = (const float*)d_in[17];
  const float* b_h1 = (const float*)d_in[18];

  char* ws = (char*)d_ws;
  const size_t MB = 1024 * 1024;
  int*   idx_ws = (int*)ws;                  // @0,   2 MiB
  float* p2T    = (float*)(ws + 2 * MB);     // @2M,  8 MiB
  float* wT     = (float*)(ws + 10 * MB);    // @10M, ~146 KiB
  const int big = (ws_size >= 28 * MB);
  float* p1T    = (float*)(ws + 11 * MB);    // @11M, 8 MiB (big only)
  float* outT   = (float*)(ws + 19 * MB);    // @19M, 8 MiB (big only)
  float* outp   = (float*)d_out;

  prep_weights_k<<<9, 256, 0, stream>>>(w_r0, w_z0, w_h0, w_r1, w_ro,
                                        w_z1, w_h1, w_fr, w_fz, wT);
  transpose_in_k<<<big ? 1024 : 512, 256, 0, stream>>>(p2, p1, p2T, big ? p1T : p2T);
  knn_k<<<512, 256, 0, stream>>>(xyz1, xyz2, idx_ws);
  fused_main_k<<<8192, 256, 0, stream>>>(xyz1, xyz2, p1, big ? p1T : p1, p2T,
                                         idx_ws, wT, b_r0, b_r1, b_z0, b_z1,
                                         b_h0, b_h1, outp, big ? outT : outp,
                                         big, big);
  if (big) transpose_out_k<<<512, 256, 0, stream>>>(outT, outp);
}

// Round 10
// 3079.428 us; speedup vs baseline: 1.0061x; 1.0061x over previous
//
#include <hip/hip_runtime.h>
#include <math.h>

// RecurrentUnitAtt on MI355X — round 10 (resubmit of v2.1; R7-R9 infra
// timeouts). R6 post-mortem: v2 ran at 2660us, VGPR=60, VALU 9.3%, WRITE
// still 182MB. Diagnosis: plsum's `#pragma unroll 1` left pl[j]
// runtime-indexed -> the accumulator arrays passed to it (za/ha/p1loc) were
// demoted to SCRATCH (rule #20). VGPR=60 is the fingerprint. Fix: fully
// unroll plsum so all register-array indices are compile-time. Single change
// vs the R6-measured kernel.

#define NPTS 4096
#define CF   64

#define OFF_R0 0
#define OFF_Z0 4288
#define OFF_H0 8576
#define OFF_R1 12864
#define OFF_RO 16960
#define OFF_Z1 21056
#define OFF_H1 25152
#define OFF_FR 29248
#define OFF_FZ 33344

__global__ __launch_bounds__(256) void prep_weights_k(
    const float* __restrict__ w_r0, const float* __restrict__ w_z0,
    const float* __restrict__ w_h0, const float* __restrict__ w_r1,
    const float* __restrict__ w_ro, const float* __restrict__ w_z1,
    const float* __restrict__ w_h1, const float* __restrict__ w_fr,
    const float* __restrict__ w_fz, float* __restrict__ wT)
{
  const float* src; float* dst; int C;
  switch (blockIdx.x) {
    case 0: src = w_r0; dst = wT + OFF_R0; C = 67; break;
    case 1: src = w_z0; dst = wT + OFF_Z0; C = 67; break;
    case 2: src = w_h0; dst = wT + OFF_H0; C = 67; break;
    case 3: src = w_r1; dst = wT + OFF_R1; C = 64; break;
    case 4: src = w_ro; dst = wT + OFF_RO; C = 64; break;
    case 5: src = w_z1; dst = wT + OFF_Z1; C = 64; break;
    case 6: src = w_h1; dst = wT + OFF_H1; C = 64; break;
    case 7: src = w_fr; dst = wT + OFF_FR; C = 64; break;
    default: src = w_fz; dst = wT + OFF_FZ; C = 64; break;
  }
  const int total = C * 64;
  for (int e = threadIdx.x; e < total; e += 256) {
    int c = e >> 6, o = e & 63;
    dst[c * 64 + o] = src[o * C + c];   // wT[c][o] = w[o][c]
  }
}

// p2 -> p2T (blocks 0..511) and p1 -> p1T (blocks 512..1023, only if launched)
__global__ __launch_bounds__(256) void transpose_in_k(
    const float* __restrict__ p2, const float* __restrict__ p1,
    float* __restrict__ p2T, float* __restrict__ p1T)
{
  __shared__ float tile[64][65];
  int id = blockIdx.x;
  const float* src; float* dst; int sub;
  if (id < 512) { sub = id;       src = p2; dst = p2T; }
  else          { sub = id - 512; src = p1; dst = p1T; }
  const int b  = sub >> 6;
  const int n0 = (sub & 63) * 64;
  src += (size_t)b * CF * NPTS;
  for (int e = threadIdx.x; e < 4096; e += 256) {
    int cc = e >> 6, nn = e & 63;
    tile[cc][nn] = src[(size_t)cc * NPTS + n0 + nn];
  }
  __syncthreads();
  float* d2 = dst + ((size_t)b * NPTS + n0) * CF;
  for (int e = threadIdx.x; e < 4096; e += 256) {
    int nn = e >> 6, cc = e & 63;
    d2[(size_t)nn * CF + cc] = tile[cc][nn];
  }
}

// outT [B,N,64] -> out [B,64,N]
__global__ __launch_bounds__(256) void transpose_out_k(
    const float* __restrict__ outT, float* __restrict__ outp)
{
  __shared__ float tile[64][65];
  const int b  = blockIdx.x >> 6;
  const int n0 = (blockIdx.x & 63) * 64;
  const float* src = outT + ((size_t)b * NPTS + n0) * CF;
  for (int e = threadIdx.x; e < 4096; e += 256) {
    int nn = e >> 6, cc = e & 63;
    tile[cc][nn] = src[(size_t)nn * CF + cc];
  }
  __syncthreads();
  float* dst = outp + (size_t)b * CF * NPTS + n0;
  for (int e = threadIdx.x; e < 4096; e += 256) {
    int cc = e >> 6, nn = e & 63;
    dst[(size_t)cc * NPTS + nn] = tile[cc][nn];
  }
}

// ---------------- kNN (unchanged from R2: passed) ----------------

__device__ __forceinline__ float max16_(const float (&ld)[16]) {
  float a0 = fmaxf(ld[0], ld[1]);
  float a1 = fmaxf(ld[2], ld[3]);
  float a2 = fmaxf(ld[4], ld[5]);
  float a3 = fmaxf(ld[6], ld[7]);
  float a4 = fmaxf(ld[8], ld[9]);
  float a5 = fmaxf(ld[10], ld[11]);
  float a6 = fmaxf(ld[12], ld[13]);
  float a7 = fmaxf(ld[14], ld[15]);
  a0 = fmaxf(a0, a1); a2 = fmaxf(a2, a3); a4 = fmaxf(a4, a5); a6 = fmaxf(a6, a7);
  return fmaxf(fmaxf(a0, a2), fmaxf(a4, a6));
}

__device__ __forceinline__ void insert16_(float (&ld)[16], int (&li)[16],
                                          float& dmax, float d, int m) {
  bool done = false;
  #pragma unroll
  for (int j = 0; j < 16; ++j) {
    bool hit = (!done) && (ld[j] == dmax);
    if (hit) { ld[j] = d; li[j] = m; }
    done = done || hit;
  }
  dmax = max16_(ld);
}

__global__ __launch_bounds__(256) void knn_k(const float* __restrict__ xyz1,
                                             const float* __restrict__ xyz2,
                                             int* __restrict__ idx_out)
{
  __shared__ float4 stage[2048];
  __shared__ float bd[4][64][17];
  __shared__ unsigned short bix[4][64][17];
  const int t    = threadIdx.x;
  const int b    = blockIdx.x >> 6;
  const int q0   = (blockIdx.x & 63) * 64;
  const int lane = t & 63;
  const int seg  = t >> 6;
  const int q    = q0 + lane;
  const float* x1b = xyz1 + (size_t)b * 3 * NPTS;
  const float* x2b = xyz2 + (size_t)b * 3 * NPTS;
  const float qx = x1b[q], qy = x1b[NPTS + q], qz = x1b[2 * NPTS + q];
  const float qq = qx * qx + qy * qy + qz * qz;
  float ld[16]; int li[16];
  #pragma unroll
  for (int j = 0; j < 16; ++j) { ld[j] = 3.4e38f; li[j] = 0; }
  float dmax = 3.4e38f;
  for (int pass = 0; pass < 2; ++pass) {
    const int mbase = pass * 2048;
    for (int i = t; i < 2048; i += 256) {
      const int mm = mbase + i;
      float px = x2b[mm], py = x2b[NPTS + mm], pz = x2b[2 * NPTS + mm];
      stage[i] = make_float4(px, py, pz, px * px + py * py + pz * pz);
    }
    __syncthreads();
    const int s0 = seg * 512;
    #pragma unroll 4
    for (int i = 0; i < 512; ++i) {
      float4 P = stage[s0 + i];
      float d = fmaf(-2.f, fmaf(qx, P.x, fmaf(qy, P.y, qz * P.z)), qq + P.w);
      if (d < dmax) insert16_(ld, li, dmax, d, mbase + s0 + i);
    }
    __syncthreads();
  }
  #pragma unroll
  for (int j = 0; j < 16; ++j) {
    bd[seg][lane][j]  = ld[j];
    bix[seg][lane][j] = (unsigned short)li[j];
  }
  __syncthreads();
  if (t < 64) {
    float md[16]; int mi[16];
    #pragma unroll
    for (int j = 0; j < 16; ++j) { md[j] = 3.4e38f; mi[j] = 0; }
    float mmax = 3.4e38f;
    for (int s = 0; s < 4; ++s) {
      #pragma unroll 4
      for (int j = 0; j < 16; ++j) {
        float d = bd[s][t][j];
        if (d < mmax) insert16_(md, mi, mmax, d, (int)bix[s][t][j]);
      }
    }
    int* op = idx_out + ((size_t)b * NPTS + q0 + t) * 16;
    #pragma unroll
    for (int j = 0; j < 16; ++j) op[j] = mi[j];
  }
}

// ---------------- fused gates v2.1: channel-split, de-scratched ----------------

__device__ __forceinline__ float sigmoidf_(float x) { return 1.0f / (1.0f + __expf(-x)); }
__device__ __forceinline__ float tanhf_(float x) {
  float s = __expf(-2.0f * fabsf(x));
  float r = (1.0f - s) / (1.0f + s);
  return x >= 0.0f ? r : -r;
}
__device__ __forceinline__ float leakyf_(float x) { return fmaxf(x, 0.0f) + 0.1f * fminf(x, 0.0f); }

__device__ __forceinline__ void fma16(const float* __restrict__ wr, float s, float (&a)[16]) {
  #pragma unroll
  for (int j4 = 0; j4 < 4; ++j4) {
    float4 wv = *(const float4*)(wr + j4 * 4);
    a[j4 * 4 + 0] = fmaf(s, wv.x, a[j4 * 4 + 0]);
    a[j4 * 4 + 1] = fmaf(s, wv.y, a[j4 * 4 + 1]);
    a[j4 * 4 + 2] = fmaf(s, wv.z, a[j4 * 4 + 2]);
    a[j4 * 4 + 3] = fmaf(s, wv.w, a[j4 * 4 + 3]);
  }
}

// a[j] += sum_{cin=0..63} in_row[cin] * wg[cin*64 + og + j]
// (rolled c4 loop is rule-#20-safe: `a` only sees compile-time indices)
__device__ __forceinline__ void mat64x16(const float* in_row, const float* __restrict__ wg,
                                         int og, float (&a)[16]) {
  #pragma unroll 1
  for (int c4 = 0; c4 < 16; ++c4) {
    float4 v = *(const float4*)(in_row + c4 * 4);     // LDS b128
    fma16(wg + (c4 * 4 + 0) * 64 + og, v.x, a);
    fma16(wg + (c4 * 4 + 1) * 64 + og, v.y, a);
    fma16(wg + (c4 * 4 + 2) * 64 + og, v.z, a);
    fma16(wg + (c4 * 4 + 3) * 64 + og, v.w, a);
  }
}

// conv0: 64 features + 3 direction rows
__device__ __forceinline__ void conv0g(const float* np_row, const float* __restrict__ wg,
                                       int og, float (&a)[16]) {
  mat64x16(np_row, wg, og, a);
  float d0 = np_row[64], d1 = np_row[65], d2 = np_row[66];
  fma16(wg + 64 * 64 + og, d0, a);
  fma16(wg + 65 * 64 + og, d1, a);
  fma16(wg + 66 * 64 + og, d2, a);
}

// Per-point [64]->[64] layer, distributed: this lane's partial over its 16-input
// group for 4 outputs (k4..k4+3), then butterfly-sum over the 4 c-lanes.
// FULLY UNROLLED (R7 fix): runtime-indexed pl[j] under `unroll 1` demoted
// caller arrays to scratch (R6: WRITE 182MB, VALU 9.3%).
__device__ __forceinline__ float4 plsum(const float (&pl)[16], const float* __restrict__ w1,
                                        int og, int k4) {
  float a0 = 0.f, a1 = 0.f, a2 = 0.f, a3 = 0.f;
  #pragma unroll
  for (int j = 0; j < 16; ++j) {
    float4 wv = *(const float4*)(w1 + (og + j) * 64 + k4);
    a0 = fmaf(pl[j], wv.x, a0);
    a1 = fmaf(pl[j], wv.y, a1);
    a2 = fmaf(pl[j], wv.z, a2);
    a3 = fmaf(pl[j], wv.w, a3);
  }
  a0 += __shfl_xor(a0, 1); a1 += __shfl_xor(a1, 1);
  a2 += __shfl_xor(a2, 1); a3 += __shfl_xor(a3, 1);
  a0 += __shfl_xor(a0, 2); a1 += __shfl_xor(a1, 2);
  a2 += __shfl_xor(a2, 2); a3 += __shfl_xor(a3, 2);
  return make_float4(a0, a1, a2, a3);
}

// block = 256 = 4 waves; wave = 1 point; lane = k*4 + c (k = neighbor, c = ch-quarter)
__global__ __launch_bounds__(256) void fused_main_k(
    const float* __restrict__ xyz1, const float* __restrict__ xyz2,
    const float* __restrict__ p1,   const float* __restrict__ p1T,
    const float* __restrict__ p2T,  const int* __restrict__ knn_idx,
    const float* __restrict__ wT,
    const float* __restrict__ b_r0, const float* __restrict__ b_r1,
    const float* __restrict__ b_z0, const float* __restrict__ b_z1,
    const float* __restrict__ b_h0, const float* __restrict__ b_h1,
    float* __restrict__ outp, float* __restrict__ outT,
    int use_p1T, int use_outT)
{
  __shared__ float np_s[4][16][68];   // 64 feat + 3 dir (+pad); 272B rows, 16B-aligned
  __shared__ float rs_s[4][16][68];   // exchange: leaky(racc), then rp
  __shared__ float p1s[4][64];
  __shared__ float frs[4][64], fzs[4][64];
  __shared__ float zs[4][64],  hs[4][64];

  const int t    = threadIdx.x;
  const int wv   = t >> 6;
  const int lane = t & 63;
  const int k    = lane >> 2;
  const int c    = lane & 3;
  const int og   = c * 16;
  const int k4   = k * 4;

  const long pid = (long)blockIdx.x * 4 + wv;        // global point id, 0..32767
  const int b = (int)(pid >> 12);
  const int n = (int)(pid & 4095);

  const float* x1b = xyz1 + (size_t)b * 3 * NPTS;
  const float* x2b = xyz2 + (size_t)b * 3 * NPTS;

  // ---- stage: p1 row, neighbor rows + direction ----
  if (use_p1T) p1s[wv][lane] = p1T[(size_t)pid * 64 + lane];
  else         p1s[wv][lane] = p1[(size_t)b * CF * NPTS + (size_t)lane * NPTS + n];

  const int m = knn_idx[(size_t)pid * 16 + k];
  {
    const float* src = p2T + ((size_t)b * NPTS + m) * 64 + og;
    float4 v0 = *(const float4*)(src);
    float4 v1 = *(const float4*)(src + 4);
    float4 v2 = *(const float4*)(src + 8);
    float4 v3 = *(const float4*)(src + 12);
    *(float4*)(&np_s[wv][k][og])      = v0;
    *(float4*)(&np_s[wv][k][og + 4])  = v1;
    *(float4*)(&np_s[wv][k][og + 8])  = v2;
    *(float4*)(&np_s[wv][k][og + 12]) = v3;
    if (c == 0) {
      np_s[wv][k][64] = x2b[m]            - x1b[n];
      np_s[wv][k][65] = x2b[NPTS + m]     - x1b[NPTS + n];
      np_s[wv][k][66] = x2b[2 * NPTS + m] - x1b[2 * NPTS + n];
    }
  }
  __syncthreads();

  // ---- fuse_r / fuse_z (per point; lane partial over its c-group, 4 outs k4..) ----
  {
    float p1loc[16];
    #pragma unroll
    for (int j4 = 0; j4 < 4; ++j4)
      *(float4*)(&p1loc[j4 * 4]) = *(const float4*)(&p1s[wv][og + j4 * 4]);
    float4 fr = plsum(p1loc, wT + OFF_FR, og, k4);
    float4 fz = plsum(p1loc, wT + OFF_FZ, og, k4);
    if (c == 0) {
      *(float4*)(&frs[wv][k4]) = fr;
      *(float4*)(&fzs[wv][k4]) = fz;
    }
  }
  __syncthreads();

  const float* nprow = &np_s[wv][k][0];

  // ---- z gate ----
  {
    float za[16];
    #pragma unroll
    for (int j4 = 0; j4 < 4; ++j4) {
      float4 bb = *(const float4*)(b_z0 + og + j4 * 4);
      float4 ff = *(const float4*)(&fzs[wv][og + j4 * 4]);
      za[j4 * 4 + 0] = bb.x + ff.x; za[j4 * 4 + 1] = bb.y + ff.y;
      za[j4 * 4 + 2] = bb.z + ff.z; za[j4 * 4 + 3] = bb.w + ff.w;
    }
    conv0g(nprow, wT + OFF_Z0, og, za);
    #pragma unroll
    for (int j = 0; j < 16; ++j) za[j] = leakyf_(za[j]);
    #pragma unroll
    for (int j = 0; j < 16; ++j) {           // max-pool over the 16 k-lanes
      float v = za[j];
      v = fmaxf(v, __shfl_xor(v, 4));
      v = fmaxf(v, __shfl_xor(v, 8));
      v = fmaxf(v, __shfl_xor(v, 16));
      v = fmaxf(v, __shfl_xor(v, 32));
      za[j] = v;
    }
    float4 s  = plsum(za, wT + OFF_Z1, og, k4);
    float4 bb = *(const float4*)(b_z1 + k4);
    if (c == 0) {
      *(float4*)(&zs[wv][k4]) = make_float4(
          sigmoidf_(s.x + bb.x), sigmoidf_(s.y + bb.y),
          sigmoidf_(s.z + bb.z), sigmoidf_(s.w + bb.w));
    }
  }

  // ---- r gate conv0 -> leaky -> LDS ----
  {
    float ra[16];
    #pragma unroll
    for (int j4 = 0; j4 < 4; ++j4) {
      float4 bb = *(const float4*)(b_r0 + og + j4 * 4);
      float4 ff = *(const float4*)(&frs[wv][og + j4 * 4]);
      ra[j4 * 4 + 0] = bb.x + ff.x; ra[j4 * 4 + 1] = bb.y + ff.y;
      ra[j4 * 4 + 2] = bb.z + ff.z; ra[j4 * 4 + 3] = bb.w + ff.w;
    }
    conv0g(nprow, wT + OFF_R0, og, ra);
    #pragma unroll
    for (int j = 0; j < 16; ++j) ra[j] = leakyf_(ra[j]);
    #pragma unroll
    for (int j4 = 0; j4 < 4; ++j4)
      *(float4*)(&rs_s[wv][k][og + j4 * 4]) =
          make_float4(ra[j4 * 4], ra[j4 * 4 + 1], ra[j4 * 4 + 2], ra[j4 * 4 + 3]);
  }
  __syncthreads();

  // ---- r1 -> sigmoid -> rp = r * p1 -> LDS (overwrite rs_s) ----
  {
    float a[16];
    #pragma unroll
    for (int j4 = 0; j4 < 4; ++j4)
      *(float4*)(&a[j4 * 4]) = *(const float4*)(b_r1 + og + j4 * 4);
    mat64x16(&rs_s[wv][k][0], wT + OFF_R1, og, a);
    float rp[16];
    #pragma unroll
    for (int j = 0; j < 16; ++j) rp[j] = sigmoidf_(a[j]) * p1s[wv][og + j];
    __syncthreads();
    #pragma unroll
    for (int j4 = 0; j4 < 4; ++j4)
      *(float4*)(&rs_s[wv][k][og + j4 * 4]) =
          make_float4(rp[j4 * 4], rp[j4 * 4 + 1], rp[j4 * 4 + 2], rp[j4 * 4 + 3]);
  }
  __syncthreads();

  // ---- h candidate: pe (rp @ w_ro) + conv0_h -> leaky -> pool -> h1 -> tanh ----
  {
    float ha[16];
    #pragma unroll
    for (int j4 = 0; j4 < 4; ++j4)
      *(float4*)(&ha[j4 * 4]) = *(const float4*)(b_h0 + og + j4 * 4);
    mat64x16(&rs_s[wv][k][0], wT + OFF_RO, og, ha);   // pe
    conv0g(nprow, wT + OFF_H0, og, ha);
    #pragma unroll
    for (int j = 0; j < 16; ++j) ha[j] = leakyf_(ha[j]);
    #pragma unroll
    for (int j = 0; j < 16; ++j) {
      float v = ha[j];
      v = fmaxf(v, __shfl_xor(v, 4));
      v = fmaxf(v, __shfl_xor(v, 8));
      v = fmaxf(v, __shfl_xor(v, 16));
      v = fmaxf(v, __shfl_xor(v, 32));
      ha[j] = v;
    }
    float4 s  = plsum(ha, wT + OFF_H1, og, k4);
    float4 bb = *(const float4*)(b_h1 + k4);
    if (c == 0) {
      *(float4*)(&hs[wv][k4]) = make_float4(
          tanhf_(s.x + bb.x), tanhf_(s.y + bb.y),
          tanhf_(s.z + bb.z), tanhf_(s.w + bb.w));
    }
  }
  __syncthreads();

  // ---- GRU update, coalesced write ----
  {
    float z = zs[wv][lane], h = hs[wv][lane], p = p1s[wv][lane];
    float o = (1.0f - z) * p + z * h;
    if (use_outT) outT[(size_t)pid * 64 + lane] = o;
    else          outp[(size_t)b * CF * NPTS + (size_t)lane * NPTS + n] = o;
  }
}

extern "C" void kernel_launch(void* const* d_in, const int* in_sizes, int n_in,
                              void* d_out, int out_size, void* d_ws, size_t ws_size,
                              hipStream_t stream)
{
  (void)in_sizes; (void)n_in; (void)out_size;
  const float* xyz1 = (const float*)d_in[0];
  const float* xyz2 = (const float*)d_in[1];
  const float* p1   = (const float*)d_in[2];
  const float* p2   = (const float*)d_in[3];
  const float* w_fr = (const float*)d_in[4];
  const float* w_fz = (const float*)d_in[5];
  const float* w_ro = (const float*)d_in[6];
  const float* w_r0 = (const float*)d_in[7];
  const float* b_r0 = (const float*)d_in[8];
  const float* w_r1 = (const float*)d_in[9];
  const float* b_r1 = (const float*)d_in[10];
  const float* w_z0 = (const float*)d_in[11];
  const float* b_z0 = (const float*)d_in[12];
  const float* w_z1 = (const float*)d_in[13];
  const float* b_z1 = (const float*)d_in[14];
  const float* w_h0 = (const float*)d_in[15];
  const float* b_h0 = (const float*)d_in[16];
  const float* w_h1 = (const float*)d_in[17];
  const float* b_h1 = (const float*)d_in[18];

  char* ws = (char*)d_ws;
  const size_t MB = 1024 * 1024;
  int*   idx_ws = (int*)ws;                  // @0,   2 MiB
  float* p2T    = (float*)(ws + 2 * MB);     // @2M,  8 MiB
  float* wT     = (float*)(ws + 10 * MB);    // @10M, ~146 KiB
  const int big = (ws_size >= 28 * MB);
  float* p1T    = (float*)(ws + 11 * MB);    // @11M, 8 MiB (big only)
  float* outT   = (float*)(ws + 19 * MB);    // @19M, 8 MiB (big only)
  float* outp   = (float*)d_out;

  prep_weights_k<<<9, 256, 0, stream>>>(w_r0, w_z0, w_h0, w_r1, w_ro,
                                        w_z1, w_h1, w_fr, w_fz, wT);
  transpose_in_k<<<big ? 1024 : 512, 256, 0, stream>>>(p2, p1, p2T, big ? p1T : p2T);
  knn_k<<<512, 256, 0, stream>>>(xyz1, xyz2, idx_ws);
  fused_main_k<<<8192, 256, 0, stream>>>(xyz1, xyz2, p1, big ? p1T : p1, p2T,
                                         idx_ws, wT, b_r0, b_r1, b_z0, b_z1,
                                         b_h0, b_h1, outp, big ? outT : outp,
                                         big, big);
  if (big) transpose_out_k<<<512, 256, 0, stream>>>(outT, outp);
}

// Round 15
// 1100.110 us; speedup vs baseline: 2.8162x; 2.7992x over previous
//
#include <hip/hip_runtime.h>
#include <math.h>

// RecurrentUnitAtt on MI355X — round 15 (resubmit of v3; R11-R14 infra
// timeouts). R10 post-mortem: scratch fixed (WRITE 182->8MB) but dur
// unchanged 2628us, VALU 9.3% => VMEM weight-stream bound: lane=(k,c)
// mapping duplicates every weight load 16x across k-lanes (51M VMEM instrs,
// 1 FMA per weight float). v3: wave = 1 point, lane = o (output channel).
// Weight ROWS of the ORIGINAL matrices stream per-lane (contiguous, ~10x
// fewer VMEM instrs); inputs broadcast from LDS (same-address reads,
// conflict-free); k-pool = in-lane fmax; fuse/bias/activations/GRU all
// lane-local. No weight transposes.

#define NPTS 4096
#define CF   64

// wpad: 3 conv0 mats padded [64][68], row-aligned 16B, col 67 = 0
#define WP_R0 0
#define WP_Z0 4352
#define WP_H0 8704

__global__ __launch_bounds__(256) void prep_pad_k(
    const float* __restrict__ w_r0, const float* __restrict__ w_z0,
    const float* __restrict__ w_h0, float* __restrict__ wpad)
{
  const float* src = (blockIdx.x == 0) ? w_r0 : (blockIdx.x == 1) ? w_z0 : w_h0;
  float* dst = wpad + blockIdx.x * 64 * 68;
  for (int e = threadIdx.x; e < 64 * 68; e += 256) {
    int o = e / 68, c = e - o * 68;
    dst[e] = (c < 67) ? src[o * 67 + c] : 0.0f;
  }
}

// p2 -> p2T (blocks 0..511) and p1 -> p1T (blocks 512..1023, only if launched)
__global__ __launch_bounds__(256) void transpose_in_k(
    const float* __restrict__ p2, const float* __restrict__ p1,
    float* __restrict__ p2T, float* __restrict__ p1T)
{
  __shared__ float tile[64][65];
  int id = blockIdx.x;
  const float* src; float* dst; int sub;
  if (id < 512) { sub = id;       src = p2; dst = p2T; }
  else          { sub = id - 512; src = p1; dst = p1T; }
  const int b  = sub >> 6;
  const int n0 = (sub & 63) * 64;
  src += (size_t)b * CF * NPTS;
  for (int e = threadIdx.x; e < 4096; e += 256) {
    int cc = e >> 6, nn = e & 63;
    tile[cc][nn] = src[(size_t)cc * NPTS + n0 + nn];
  }
  __syncthreads();
  float* d2 = dst + ((size_t)b * NPTS + n0) * CF;
  for (int e = threadIdx.x; e < 4096; e += 256) {
    int nn = e >> 6, cc = e & 63;
    d2[(size_t)nn * CF + cc] = tile[cc][nn];
  }
}

// outT [B,N,64] -> out [B,64,N]
__global__ __launch_bounds__(256) void transpose_out_k(
    const float* __restrict__ outT, float* __restrict__ outp)
{
  __shared__ float tile[64][65];
  const int b  = blockIdx.x >> 6;
  const int n0 = (blockIdx.x & 63) * 64;
  const float* src = outT + ((size_t)b * NPTS + n0) * CF;
  for (int e = threadIdx.x; e < 4096; e += 256) {
    int nn = e >> 6, cc = e & 63;
    tile[cc][nn] = src[(size_t)nn * CF + cc];
  }
  __syncthreads();
  float* dst = outp + (size_t)b * CF * NPTS + n0;
  for (int e = threadIdx.x; e < 4096; e += 256) {
    int cc = e >> 6, nn = e & 63;
    dst[(size_t)cc * NPTS + nn] = tile[cc][nn];
  }
}

// ---------------- kNN (unchanged from R2: passed) ----------------

__device__ __forceinline__ float max16_(const float (&ld)[16]) {
  float a0 = fmaxf(ld[0], ld[1]);
  float a1 = fmaxf(ld[2], ld[3]);
  float a2 = fmaxf(ld[4], ld[5]);
  float a3 = fmaxf(ld[6], ld[7]);
  float a4 = fmaxf(ld[8], ld[9]);
  float a5 = fmaxf(ld[10], ld[11]);
  float a6 = fmaxf(ld[12], ld[13]);
  float a7 = fmaxf(ld[14], ld[15]);
  a0 = fmaxf(a0, a1); a2 = fmaxf(a2, a3); a4 = fmaxf(a4, a5); a6 = fmaxf(a6, a7);
  return fmaxf(fmaxf(a0, a2), fmaxf(a4, a6));
}

__device__ __forceinline__ void insert16_(float (&ld)[16], int (&li)[16],
                                          float& dmax, float d, int m) {
  bool done = false;
  #pragma unroll
  for (int j = 0; j < 16; ++j) {
    bool hit = (!done) && (ld[j] == dmax);
    if (hit) { ld[j] = d; li[j] = m; }
    done = done || hit;
  }
  dmax = max16_(ld);
}

__global__ __launch_bounds__(256) void knn_k(const float* __restrict__ xyz1,
                                             const float* __restrict__ xyz2,
                                             int* __restrict__ idx_out)
{
  __shared__ float4 stage[2048];
  __shared__ float bd[4][64][17];
  __shared__ unsigned short bix[4][64][17];
  const int t    = threadIdx.x;
  const int b    = blockIdx.x >> 6;
  const int q0   = (blockIdx.x & 63) * 64;
  const int lane = t & 63;
  const int seg  = t >> 6;
  const int q    = q0 + lane;
  const float* x1b = xyz1 + (size_t)b * 3 * NPTS;
  const float* x2b = xyz2 + (size_t)b * 3 * NPTS;
  const float qx = x1b[q], qy = x1b[NPTS + q], qz = x1b[2 * NPTS + q];
  const float qq = qx * qx + qy * qy + qz * qz;
  float ld[16]; int li[16];
  #pragma unroll
  for (int j = 0; j < 16; ++j) { ld[j] = 3.4e38f; li[j] = 0; }
  float dmax = 3.4e38f;
  for (int pass = 0; pass < 2; ++pass) {
    const int mbase = pass * 2048;
    for (int i = t; i < 2048; i += 256) {
      const int mm = mbase + i;
      float px = x2b[mm], py = x2b[NPTS + mm], pz = x2b[2 * NPTS + mm];
      stage[i] = make_float4(px, py, pz, px * px + py * py + pz * pz);
    }
    __syncthreads();
    const int s0 = seg * 512;
    #pragma unroll 4
    for (int i = 0; i < 512; ++i) {
      float4 P = stage[s0 + i];
      float d = fmaf(-2.f, fmaf(qx, P.x, fmaf(qy, P.y, qz * P.z)), qq + P.w);
      if (d < dmax) insert16_(ld, li, dmax, d, mbase + s0 + i);
    }
    __syncthreads();
  }
  #pragma unroll
  for (int j = 0; j < 16; ++j) {
    bd[seg][lane][j]  = ld[j];
    bix[seg][lane][j] = (unsigned short)li[j];
  }
  __syncthreads();
  if (t < 64) {
    float md[16]; int mi[16];
    #pragma unroll
    for (int j = 0; j < 16; ++j) { md[j] = 3.4e38f; mi[j] = 0; }
    float mmax = 3.4e38f;
    for (int s = 0; s < 4; ++s) {
      #pragma unroll 4
      for (int j = 0; j < 16; ++j) {
        float d = bd[s][t][j];
        if (d < mmax) insert16_(md, mi, mmax, d, (int)bix[s][t][j]);
      }
    }
    int* op = idx_out + ((size_t)b * NPTS + q0 + t) * 16;
    #pragma unroll
    for (int j = 0; j < 16; ++j) op[j] = mi[j];
  }
}

// ---------------- fused gates v3: lane = output channel ----------------

__device__ __forceinline__ float sigmoidf_(float x) { return 1.0f / (1.0f + __expf(-x)); }
__device__ __forceinline__ float tanhf_(float x) {
  float s = __expf(-2.0f * fabsf(x));
  float r = (1.0f - s) / (1.0f + s);
  return x >= 0.0f ? r : -r;
}
__device__ __forceinline__ float leakyf_(float x) { return fmaxf(x, 0.0f) + 0.1f * fminf(x, 0.0f); }

// acc[k] += sum_{cin=0..63} rows[k*STRIDE+cin] * wrow[cin]
// rows: LDS, broadcast (all lanes same addr). wrow: per-lane global row.
template<int STRIDE>
__device__ __forceinline__ void gemv16(const float* rows, const float* __restrict__ wrow,
                                       float (&acc)[16]) {
  #pragma unroll 4
  for (int c4 = 0; c4 < 16; ++c4) {
    float4 w4 = *(const float4*)(wrow + c4 * 4);
    #pragma unroll
    for (int k = 0; k < 16; ++k) {
      float4 v = *(const float4*)(rows + k * STRIDE + c4 * 4);
      acc[k] = fmaf(v.x, w4.x, acc[k]);
      acc[k] = fmaf(v.y, w4.y, acc[k]);
      acc[k] = fmaf(v.z, w4.z, acc[k]);
      acc[k] = fmaf(v.w, w4.w, acc[k]);
    }
  }
}

// conv0 tail: cins 64..67 (d0,d1,d2,0); np[..][67]=0, wpad[..][67]=0
__device__ __forceinline__ void gemv16_tail(const float* rows, const float* __restrict__ wrow,
                                            float (&acc)[16]) {
  float4 w4 = *(const float4*)(wrow + 64);
  #pragma unroll
  for (int k = 0; k < 16; ++k) {
    float4 v = *(const float4*)(rows + k * 68 + 64);
    acc[k] = fmaf(v.x, w4.x, acc[k]);
    acc[k] = fmaf(v.y, w4.y, acc[k]);
    acc[k] = fmaf(v.z, w4.z, acc[k]);
    acc[k] = fmaf(v.w, w4.w, acc[k]);
  }
}

// a += sum_{cin} vec[cin] * wrow[cin]   (vec: LDS broadcast; wrow: per-lane row)
__device__ __forceinline__ float gemv1(const float* vec, const float* __restrict__ wrow,
                                       float a) {
  #pragma unroll 4
  for (int c4 = 0; c4 < 16; ++c4) {
    float4 w4 = *(const float4*)(wrow + c4 * 4);
    float4 v  = *(const float4*)(vec + c4 * 4);
    a = fmaf(v.x, w4.x, a);
    a = fmaf(v.y, w4.y, a);
    a = fmaf(v.z, w4.z, a);
    a = fmaf(v.w, w4.w, a);
  }
  return a;
}

// block = 256 = 4 waves; wave = 1 point; lane = output channel o (0..63)
__global__ __launch_bounds__(256) void fused_main_k(
    const float* __restrict__ xyz1, const float* __restrict__ xyz2,
    const float* __restrict__ p1,   const float* __restrict__ p1T,
    const float* __restrict__ p2T,  const int* __restrict__ knn_idx,
    const float* __restrict__ wpad,
    const float* __restrict__ w_fr, const float* __restrict__ w_fz,
    const float* __restrict__ w_r1, const float* __restrict__ w_ro,
    const float* __restrict__ w_z1, const float* __restrict__ w_h1,
    const float* __restrict__ b_r0, const float* __restrict__ b_r1,
    const float* __restrict__ b_z0, const float* __restrict__ b_z1,
    const float* __restrict__ b_h0, const float* __restrict__ b_h1,
    float* __restrict__ outp, float* __restrict__ outT,
    int use_p1T, int use_outT)
{
  __shared__ __align__(16) float np_s[4][16][68];  // 64 feat + d0,d1,d2 + 0-pad
  __shared__ __align__(16) float rs_s[4][16][64];  // leaky(r) rows, then rp rows
  __shared__ __align__(16) float pool_s[4][64];    // zpool, then hpool
  __shared__ __align__(16) float p1_s[4][64];
  __shared__ int mi_s[4][16];

  const int t    = threadIdx.x;
  const int wv   = t >> 6;
  const int lane = t & 63;          // = output channel o
  const long pid = (long)blockIdx.x * 4 + wv;
  const int b = (int)(pid >> 12);
  const int n = (int)(pid & 4095);

  // ---- stage p1 row (lane-local value + LDS broadcast copy) ----
  float p1v;
  if (use_p1T) p1v = p1T[(size_t)pid * 64 + lane];
  else         p1v = p1[(size_t)b * CF * NPTS + (size_t)lane * NPTS + n];
  p1_s[wv][lane] = p1v;

  if (lane < 16) mi_s[wv][lane] = knn_idx[(size_t)pid * 16 + lane];
  __syncthreads();

  // ---- stage neighbor rows (lane -> row k=lane>>2, 16-float chunk lane&3) ----
  {
    const int k  = lane >> 2;
    const int ch = (lane & 3) * 16;
    const int m  = mi_s[wv][k];
    const float* src = p2T + ((size_t)b * NPTS + m) * 64 + ch;
    float4 v0 = *(const float4*)(src);
    float4 v1 = *(const float4*)(src + 4);
    float4 v2 = *(const float4*)(src + 8);
    float4 v3 = *(const float4*)(src + 12);
    *(float4*)(&np_s[wv][k][ch])      = v0;
    *(float4*)(&np_s[wv][k][ch + 4])  = v1;
    *(float4*)(&np_s[wv][k][ch + 8])  = v2;
    *(float4*)(&np_s[wv][k][ch + 12]) = v3;
  }
  if (lane < 16) {
    const int k = lane;
    const int m = mi_s[wv][k];
    const float* x1b = xyz1 + (size_t)b * 3 * NPTS;
    const float* x2b = xyz2 + (size_t)b * 3 * NPTS;
    np_s[wv][k][64] = x2b[m]            - x1b[n];
    np_s[wv][k][65] = x2b[NPTS + m]     - x1b[NPTS + n];
    np_s[wv][k][66] = x2b[2 * NPTS + m] - x1b[2 * NPTS + n];
    np_s[wv][k][67] = 0.0f;
  }
  __syncthreads();

  const float* nps = &np_s[wv][0][0];
  const float* rss = &rs_s[wv][0][0];

  // ---- fuse_r / fuse_z: lane-local scalars ----
  float fr = gemv1(&p1_s[wv][0], w_fr + lane * 64, 0.0f);
  float fz = gemv1(&p1_s[wv][0], w_fz + lane * 64, 0.0f);

  // ---- z gate ----
  float zval;
  {
    float za[16];
    const float bz = b_z0[lane] + fz;
    #pragma unroll
    for (int k = 0; k < 16; ++k) za[k] = bz;
    gemv16<68>(nps, wpad + WP_Z0 + lane * 68, za);
    gemv16_tail(nps, wpad + WP_Z0 + lane * 68, za);
    #pragma unroll
    for (int k = 0; k < 16; ++k) za[k] = leakyf_(za[k]);
    pool_s[wv][lane] = max16_(za);          // in-lane k-pool, no shuffles
  }
  __syncthreads();
  zval = sigmoidf_(gemv1(&pool_s[wv][0], w_z1 + lane * 64, b_z1[lane]));

  // ---- r gate conv0 -> leaky -> rows to LDS ----
  {
    float ra[16];
    const float br = b_r0[lane] + fr;
    #pragma unroll
    for (int k = 0; k < 16; ++k) ra[k] = br;
    gemv16<68>(nps, wpad + WP_R0 + lane * 68, ra);
    gemv16_tail(nps, wpad + WP_R0 + lane * 68, ra);
    #pragma unroll
    for (int k = 0; k < 16; ++k) rs_s[wv][k][lane] = leakyf_(ra[k]);
  }
  __syncthreads();

  // ---- r1 -> sigmoid -> rp = r * p1, overwrite rs rows ----
  {
    float a2[16];
    const float br1 = b_r1[lane];
    #pragma unroll
    for (int k = 0; k < 16; ++k) a2[k] = br1;
    gemv16<64>(rss, w_r1 + lane * 64, a2);
    float rp[16];
    #pragma unroll
    for (int k = 0; k < 16; ++k) rp[k] = sigmoidf_(a2[k]) * p1v;
    __syncthreads();                        // all r1 reads complete
    #pragma unroll
    for (int k = 0; k < 16; ++k) rs_s[wv][k][lane] = rp[k];
  }
  __syncthreads();

  // ---- h: pe(rp @ w_ro row) + conv0_h -> leaky -> pool -> h1 -> tanh ----
  float hval;
  {
    float ha[16];
    const float bh = b_h0[lane];
    #pragma unroll
    for (int k = 0; k < 16; ++k) ha[k] = bh;
    gemv16<64>(rss, w_ro + lane * 64, ha);                 // pe
    gemv16<68>(nps, wpad + WP_H0 + lane * 68, ha);         // conv0_h
    gemv16_tail(nps, wpad + WP_H0 + lane * 68, ha);
    #pragma unroll
    for (int k = 0; k < 16; ++k) ha[k] = leakyf_(ha[k]);
    float hp = max16_(ha);
    __syncthreads();                        // pool_s reuse (z1 reads done)
    pool_s[wv][lane] = hp;
  }
  __syncthreads();
  hval = tanhf_(gemv1(&pool_s[wv][0], w_h1 + lane * 64, b_h1[lane]));

  // ---- GRU update ----
  float oval = (1.0f - zval) * p1v + zval * hval;
  if (use_outT) outT[(size_t)pid * 64 + lane] = oval;
  else          outp[(size_t)b * CF * NPTS + (size_t)lane * NPTS + n] = oval;
}

extern "C" void kernel_launch(void* const* d_in, const int* in_sizes, int n_in,
                              void* d_out, int out_size, void* d_ws, size_t ws_size,
                              hipStream_t stream)
{
  (void)in_sizes; (void)n_in; (void)out_size;
  const float* xyz1 = (const float*)d_in[0];
  const float* xyz2 = (const float*)d_in[1];
  const float* p1   = (const float*)d_in[2];
  const float* p2   = (const float*)d_in[3];
  const float* w_fr = (const float*)d_in[4];
  const float* w_fz = (const float*)d_in[5];
  const float* w_ro = (const float*)d_in[6];
  const float* w_r0 = (const float*)d_in[7];
  const float* b_r0 = (const float*)d_in[8];
  const float* w_r1 = (const float*)d_in[9];
  const float* b_r1 = (const float*)d_in[10];
  const float* w_z0 = (const float*)d_in[11];
  const float* b_z0 = (const float*)d_in[12];
  const float* w_z1 = (const float*)d_in[13];
  const float* b_z1 = (const float*)d_in[14];
  const float* w_h0 = (const float*)d_in[15];
  const float* b_h0 = (const float*)d_in[16];
  const float* w_h1 = (const float*)d_in[17];
  const float* b_h1 = (const float*)d_in[18];

  char* ws = (char*)d_ws;
  const size_t MB = 1024 * 1024;
  int*   idx_ws = (int*)ws;                  // @0,   2 MiB
  float* p2T    = (float*)(ws + 2 * MB);     // @2M,  8 MiB
  float* wpad   = (float*)(ws + 10 * MB);    // @10M, 52 KiB (3x64x68)
  const int big = (ws_size >= 28 * MB);
  float* p1T    = (float*)(ws + 11 * MB);    // @11M, 8 MiB (big only)
  float* outT   = (float*)(ws + 19 * MB);    // @19M, 8 MiB (big only)
  float* outp   = (float*)d_out;

  prep_pad_k<<<3, 256, 0, stream>>>(w_r0, w_z0, w_h0, wpad);
  transpose_in_k<<<big ? 1024 : 512, 256, 0, stream>>>(p2, p1, p2T, big ? p1T : p2T);
  knn_k<<<512, 256, 0, stream>>>(xyz1, xyz2, idx_ws);
  fused_main_k<<<8192, 256, 0, stream>>>(xyz1, xyz2, p1, big ? p1T : p1, p2T,
                                         idx_ws, wpad, w_fr, w_fz, w_r1, w_ro,
                                         w_z1, w_h1, b_r0, b_r1, b_z0, b_z1,
                                         b_h0, b_h1, outp, big ? outT : outp,
                                         big, big);
  if (big) transpose_out_k<<<512, 256, 0, stream>>>(outT, outp);
}